// Round 4
// baseline (5293.991 us; speedup 1.0000x reference)
//
#include <hip/hip_runtime.h>
#include <cstdint>

#define TSEQ 4096
#define DMODEL 2048
#define NH 16
#define HDK 128
#define HDV 256
#define KEYDIM (NH * HDK)   // 2048
#define VALDIM (NH * HDV)   // 4096
#define SCHUNK 32

static __device__ __forceinline__ float sigmoidf_(float x) { return 1.f / (1.f + __expf(-x)); }
static __device__ __forceinline__ float siluf_(float x)    { return x / (1.f + __expf(-x)); }
static __device__ __forceinline__ float softplusf_(float x){ return (x > 20.f) ? x : log1pf(__expf(x)); }

// block-wide sum; NW = number of waves in block; call exactly once per red[] use
template <int NW>
static __device__ __forceinline__ float block_sum(float v, float* red) {
  #pragma unroll
  for (int off = 1; off < 64; off <<= 1) v += __shfl_xor(v, off);
  if ((threadIdx.x & 63) == 0) red[threadIdx.x >> 6] = v;
  __syncthreads();
  float t = 0.f;
  #pragma unroll
  for (int i = 0; i < NW; ++i) t += red[i];
  return t;
}

// ---------------- rmsnorm of input rows ----------------
__global__ __launch_bounds__(256) void k_rms_row(const float* __restrict__ in,
                                                 const float* __restrict__ w,
                                                 float* __restrict__ out) {
  __shared__ float red[4];
  const int t = blockIdx.x;
  const float4* r4 = (const float4*)(in + (size_t)t * DMODEL);
  float4 v0 = r4[threadIdx.x];
  float4 v1 = r4[threadIdx.x + 256];
  float s = v0.x*v0.x + v0.y*v0.y + v0.z*v0.z + v0.w*v0.w
          + v1.x*v1.x + v1.y*v1.y + v1.z*v1.z + v1.w*v1.w;
  float tot = block_sum<4>(s, red);
  float inv = rsqrtf(tot * (1.f / DMODEL) + 1e-5f);
  const float4* w4 = (const float4*)w;
  float4 wa = w4[threadIdx.x], wb = w4[threadIdx.x + 256];
  float4 o0, o1;
  o0.x = v0.x * inv * wa.x; o0.y = v0.y * inv * wa.y; o0.z = v0.z * inv * wa.z; o0.w = v0.w * inv * wa.w;
  o1.x = v1.x * inv * wb.x; o1.y = v1.y * inv * wb.y; o1.z = v1.z * inv * wb.z; o1.w = v1.w * inv * wb.w;
  float4* dst = (float4*)(out + (size_t)t * DMODEL);
  dst[threadIdx.x] = o0;
  dst[threadIdx.x + 256] = o1;
}

// ---------------- final residual + rmsnorm (in-place on io) ----------------
__global__ __launch_bounds__(256) void k_final_rms(const float* __restrict__ x,
                                                   const float* __restrict__ w,
                                                   float* __restrict__ io) {
  __shared__ float red[4];
  const int t = blockIdx.x;
  const float4* x4 = (const float4*)(x + (size_t)t * DMODEL);
  float4* io4 = (float4*)(io + (size_t)t * DMODEL);
  float4 v0 = x4[threadIdx.x];
  float4 v1 = x4[threadIdx.x + 256];
  float4 u0 = io4[threadIdx.x];
  float4 u1 = io4[threadIdx.x + 256];
  v0.x += u0.x; v0.y += u0.y; v0.z += u0.z; v0.w += u0.w;
  v1.x += u1.x; v1.y += u1.y; v1.z += u1.z; v1.w += u1.w;
  float s = v0.x*v0.x + v0.y*v0.y + v0.z*v0.z + v0.w*v0.w
          + v1.x*v1.x + v1.y*v1.y + v1.z*v1.z + v1.w*v1.w;
  float tot = block_sum<4>(s, red);
  float inv = rsqrtf(tot * (1.f / DMODEL) + 1e-5f);
  const float4* w4 = (const float4*)w;
  float4 wa = w4[threadIdx.x], wb = w4[threadIdx.x + 256];
  float4 o0, o1;
  o0.x = v0.x * inv * wa.x; o0.y = v0.y * inv * wa.y; o0.z = v0.z * inv * wa.z; o0.w = v0.w * inv * wa.w;
  o1.x = v1.x * inv * wb.x; o1.y = v1.y * inv * wb.y; o1.z = v1.z * inv * wb.z; o1.w = v1.w * inv * wb.w;
  io4[threadIdx.x] = o0;
  io4[threadIdx.x + 256] = o1;
}

// ---------------- fp32 GEMM, C[m][n] = sum_k A[m][k] * B[n][k] ----------------
static __device__ __forceinline__ int gslot(int m) {
  // bijection on 0..31: out = [b4][b0][b3 b2 b1]
  return ((m >> 1) & 7) | ((m & 1) << 3) | ((m >> 4) << 4);
}

__global__ __launch_bounds__(256, 2) void k_gemm_tn(const float* __restrict__ A,
                                                    const float* __restrict__ B,
                                                    float* __restrict__ C,
                                                    int N, int K) {
  __shared__ __align__(16) float As[16 * 128];
  __shared__ __align__(16) float Bs[16 * 128];
  const int bm = blockIdx.y * 128, bn = blockIdx.x * 128;
  const int tid = threadIdx.x;
  const int tr = tid >> 4, tc = tid & 15;
  const int r = tid >> 1, half = tid & 1;
  const int cslot = gslot(r >> 2) * 4 + (r & 3);
  const int as0 = gslot(2 * tr), as1 = gslot(2 * tr + 1);
  const int bs0 = gslot(2 * tc), bs1 = gslot(2 * tc + 1);
  float acc[8][8];
  #pragma unroll
  for (int i = 0; i < 8; ++i)
    #pragma unroll
    for (int j = 0; j < 8; ++j) acc[i][j] = 0.f;

  const float* Arow = A + (size_t)(bm + r) * K + half * 8;
  const float* Brow = B + (size_t)(bn + r) * K + half * 8;
  const bool bvalid = (bn + r) < N;

  for (int k0 = 0; k0 < K; k0 += 16) {
    float4 a0 = *(const float4*)(Arow + k0);
    float4 a1 = *(const float4*)(Arow + k0 + 4);
    float4 b0 = make_float4(0.f, 0.f, 0.f, 0.f);
    float4 b1 = make_float4(0.f, 0.f, 0.f, 0.f);
    if (bvalid) {
      b0 = *(const float4*)(Brow + k0);
      b1 = *(const float4*)(Brow + k0 + 4);
    }
    __syncthreads();
    {
      const float* ap0 = (const float*)&a0;
      const float* ap1 = (const float*)&a1;
      const float* bp0 = (const float*)&b0;
      const float* bp1 = (const float*)&b1;
      #pragma unroll
      for (int j = 0; j < 4; ++j) {
        As[(half * 8 + j) * 128 + cslot]     = ap0[j];
        As[(half * 8 + 4 + j) * 128 + cslot] = ap1[j];
        Bs[(half * 8 + j) * 128 + cslot]     = bp0[j];
        Bs[(half * 8 + 4 + j) * 128 + cslot] = bp1[j];
      }
    }
    __syncthreads();
    #pragma unroll
    for (int kk = 0; kk < 16; ++kk) {
      const float4* ar = (const float4*)(As + kk * 128);
      const float4* br = (const float4*)(Bs + kk * 128);
      float4 av0 = ar[as0], av1 = ar[as1];
      float4 bv0 = br[bs0], bv1 = br[bs1];
      float a[8] = {av0.x, av0.y, av0.z, av0.w, av1.x, av1.y, av1.z, av1.w};
      float b[8] = {bv0.x, bv0.y, bv0.z, bv0.w, bv1.x, bv1.y, bv1.z, bv1.w};
      #pragma unroll
      for (int i = 0; i < 8; ++i)
        #pragma unroll
        for (int j = 0; j < 8; ++j)
          acc[i][j] = fmaf(a[i], b[j], acc[i][j]);
    }
  }
  // epilogue
  if (bn + tc * 8 < N) {
    #pragma unroll
    for (int i = 0; i < 8; ++i) {
      float4 c0 = make_float4(acc[i][0], acc[i][1], acc[i][2], acc[i][3]);
      float4 c1 = make_float4(acc[i][4], acc[i][5], acc[i][6], acc[i][7]);
      float* crow = C + (size_t)(bm + tr * 8 + i) * N + bn + tc * 8;
      *(float4*)(crow) = c0;
      *(float4*)(crow + 4) = c1;
    }
  }
}

// ---------------- a/b projections (N=16 each) + activations ----------------
__global__ __launch_bounds__(256) void k_ab(const float* __restrict__ xn,
                                            const float* __restrict__ a_proj,
                                            const float* __restrict__ b_proj,
                                            const float* __restrict__ A_log,
                                            const float* __restrict__ dt_bias,
                                            float* __restrict__ g_arr,
                                            float* __restrict__ b_arr) {
  __shared__ __align__(16) float xrow[DMODEL];
  const int t = blockIdx.x;
  const float4* src = (const float4*)(xn + (size_t)t * DMODEL);
  ((float4*)xrow)[threadIdx.x] = src[threadIdx.x];
  ((float4*)xrow)[threadIdx.x + 256] = src[threadIdx.x + 256];
  __syncthreads();
  const int d = threadIdx.x >> 3, p = threadIdx.x & 7;   // 32 dots x 8 lanes
  const float* wrow = (d < NH) ? (a_proj + (size_t)d * DMODEL)
                               : (b_proj + (size_t)(d - NH) * DMODEL);
  const float4* w4 = (const float4*)wrow;
  const float4* x4 = (const float4*)xrow;
  float s = 0.f;
  #pragma unroll 4
  for (int j = p; j < DMODEL / 4; j += 8) {
    float4 xv = x4[j], wv = w4[j];
    s += xv.x * wv.x + xv.y * wv.y + xv.z * wv.z + xv.w * wv.w;
  }
  s += __shfl_xor(s, 1);
  s += __shfl_xor(s, 2);
  s += __shfl_xor(s, 4);
  if (p == 0) {
    if (d < NH) {
      float dt = softplusf_(s + dt_bias[d]);
      g_arr[t * NH + d] = -__expf(A_log[d]) * dt;
    } else {
      b_arr[t * NH + (d - NH)] = sigmoidf_(s);
    }
  }
}

// ---------------- conv(K=4) + silu + l2norm for q/k; writes [H][T][128] ----------------
__global__ __launch_bounds__(128) void k_conv_qk(const float* __restrict__ pre,
                                                 const float* __restrict__ w,
                                                 float* __restrict__ out,
                                                 float scale) {
  __shared__ float red[2];
  const int t = blockIdx.x, hh = blockIdx.y, c = threadIdx.x;
  const int ch = hh * HDK + c;
  float acc = 0.f;
  #pragma unroll
  for (int i = 0; i < 4; ++i) {
    int tt = t - 3 + i;
    float xv = (tt >= 0) ? pre[(size_t)tt * KEYDIM + ch] : 0.f;
    acc = fmaf(w[ch * 4 + i], xv, acc);
  }
  float y = siluf_(acc);
  float tot = block_sum<2>(y * y, red);
  float inv = scale / fmaxf(sqrtf(tot), 1e-12f);
  out[((size_t)hh * TSEQ + t) * HDK + c] = y * inv;
}

// ---------------- conv(K=4) + silu for v; writes [H][T][256] ----------------
__global__ __launch_bounds__(256) void k_conv_v(const float* __restrict__ pre,
                                                const float* __restrict__ w,
                                                float* __restrict__ out) {
  const int t = blockIdx.x, hh = blockIdx.y, c = threadIdx.x;
  const int ch = hh * HDV + c;
  float acc = 0.f;
  #pragma unroll
  for (int i = 0; i < 4; ++i) {
    int tt = t - 3 + i;
    float xv = (tt >= 0) ? pre[(size_t)tt * VALDIM + ch] : 0.f;
    acc = fmaf(w[ch * 4 + i], xv, acc);
  }
  out[((size_t)hh * TSEQ + t) * HDV + c] = siluf_(acc);
}

// ---------------- gated delta scan ----------------
// grid (8 dv-slices, 16 heads), 256 threads. Thread (dv = tid>>3, dkg = tid&7)
// owns h[dkg*16 .. +15][dv] in registers. k/q staged per 32-step chunk in LDS
// with chunk-swizzle slot(m)=4*(m&7)+(m>>3) so per-step b128 reads are 2-way.
static __device__ __forceinline__ int sslot(int m) { return 4 * (m & 7) + (m >> 3); }

__global__ __launch_bounds__(256) void k_scan(const float* __restrict__ qs,
                                              const float* __restrict__ ks,
                                              const float* __restrict__ vs,
                                              const float* __restrict__ g_arr,
                                              const float* __restrict__ b_arr,
                                              float* __restrict__ o) {
  __shared__ __align__(16) float kt[SCHUNK * HDK];
  __shared__ __align__(16) float qt[SCHUNK * HDK];
  __shared__ __align__(16) float vt[SCHUNK * 32];
  __shared__ float gt[SCHUNK], bt[SCHUNK];
  const int hh = blockIdx.y, dvb = blockIdx.x;
  const int tid = threadIdx.x;
  const int dv = tid >> 3, dkg = tid & 7;
  const int s0 = 16 * (dkg & 1) + (dkg >> 1);  // slot of chunk 4*dkg+r is s0+4r
  float hreg[16];
  #pragma unroll
  for (int i = 0; i < 16; ++i) hreg[i] = 0.f;
  const float* kb = ks + (size_t)hh * TSEQ * HDK;
  const float* qb = qs + (size_t)hh * TSEQ * HDK;
  const float* vb = vs + (size_t)hh * TSEQ * HDV + dvb * 32;

  for (int t0 = 0; t0 < TSEQ; t0 += SCHUNK) {
    __syncthreads();
    #pragma unroll
    for (int i = 0; i < 4; ++i) {          // 32*128 floats = 1024 float4
      int f4 = tid + i * 256;
      int tt = f4 >> 5, m = f4 & 31;
      int off = tt * HDK + sslot(m) * 4;
      *(float4*)(kt + off) = *(const float4*)(kb + (size_t)(t0 + tt) * HDK + m * 4);
      *(float4*)(qt + off) = *(const float4*)(qb + (size_t)(t0 + tt) * HDK + m * 4);
    }
    {
      int tt = tid >> 3, cc = tid & 7;     // 32*32 floats = 256 float4
      *(float4*)(vt + tt * 32 + cc * 4) =
          *(const float4*)(vb + (size_t)(t0 + tt) * HDV + cc * 4);
    }
    if (tid < SCHUNK) {
      gt[tid] = g_arr[(t0 + tid) * NH + hh];
      bt[tid] = b_arr[(t0 + tid) * NH + hh];
    }
    __syncthreads();

    for (int tt = 0; tt < SCHUNK; ++tt) {
      const float4* kr = (const float4*)(kt + tt * HDK);
      const float4* qr = (const float4*)(qt + tt * HDK);
      float ka[16], qa[16];
      *(float4*)(ka + 0)  = kr[s0];      *(float4*)(ka + 4)  = kr[s0 + 4];
      *(float4*)(ka + 8)  = kr[s0 + 8];  *(float4*)(ka + 12) = kr[s0 + 12];
      *(float4*)(qa + 0)  = qr[s0];      *(float4*)(qa + 4)  = qr[s0 + 4];
      *(float4*)(qa + 8)  = qr[s0 + 8];  *(float4*)(qa + 12) = qr[s0 + 12];
      float eg = __expf(gt[tt]);
      float vv = vt[tt * 32 + dv];
      float bb = bt[tt];
      float skh = 0.f, sqh = 0.f, sqk = 0.f;
      #pragma unroll
      for (int i = 0; i < 16; ++i) {
        skh = fmaf(ka[i], hreg[i], skh);
        sqh = fmaf(qa[i], hreg[i], sqh);
        sqk = fmaf(qa[i], ka[i], sqk);
      }
      skh += __shfl_xor(skh, 1); sqh += __shfl_xor(sqh, 1); sqk += __shfl_xor(sqk, 1);
      skh += __shfl_xor(skh, 2); sqh += __shfl_xor(sqh, 2); sqk += __shfl_xor(sqk, 2);
      skh += __shfl_xor(skh, 4); sqh += __shfl_xor(sqh, 4); sqk += __shfl_xor(sqk, 4);
      float vadj = (vv - eg * skh) * bb;
      float oo = fmaf(eg, sqh, sqk * vadj);
      if (dkg == 0)
        o[(size_t)(t0 + tt) * VALDIM + hh * HDV + dvb * 32 + dv] = oo;
      #pragma unroll
      for (int i = 0; i < 16; ++i) hreg[i] = fmaf(hreg[i], eg, ka[i] * vadj);
    }
  }
}

// ---------------- per-(t,h) rmsnorm of o * silu(gate) ----------------
__global__ __launch_bounds__(256) void k_ognorm(const float* __restrict__ o,
                                                const float* __restrict__ gate,
                                                const float* __restrict__ w,
                                                float* __restrict__ og) {
  __shared__ float red[4];
  const int t = blockIdx.x, hh = blockIdx.y, c = threadIdx.x;
  size_t idx = (size_t)t * VALDIM + hh * HDV + c;
  float v = o[idx];
  float tot = block_sum<4>(v * v, red);
  float inv = rsqrtf(tot * (1.f / HDV) + 1e-5f);
  float gv = gate[idx];
  og[idx] = v * inv * w[c] * siluf_(gv);
}

extern "C" void kernel_launch(void* const* d_in, const int* in_sizes, int n_in,
                              void* d_out, int out_size, void* d_ws, size_t ws_size,
                              hipStream_t stream) {
  const float* x        = (const float*)d_in[0];
  const float* norm_s   = (const float*)d_in[1];
  const float* final_s  = (const float*)d_in[2];
  const float* wq       = (const float*)d_in[3];
  const float* wk       = (const float*)d_in[4];
  const float* wv       = (const float*)d_in[5];
  const float* qconv    = (const float*)d_in[6];
  const float* kconv    = (const float*)d_in[7];
  const float* vconv    = (const float*)d_in[8];
  const float* a_proj   = (const float*)d_in[9];
  const float* A_log    = (const float*)d_in[10];
  const float* dt_bias  = (const float*)d_in[11];
  const float* b_proj   = (const float*)d_in[12];
  const float* g_proj   = (const float*)d_in[13];
  const float* o_norm_s = (const float*)d_in[14];
  const float* wo       = (const float*)d_in[15];
  float* out = (float*)d_out;
  float* ws  = (float*)d_ws;

  const size_t M1 = 1u << 20;
  // Compact live-range-overlapped workspace: peak = 56*M1 + 128K floats
  // (~224.5 MB; prior 336 MB layout likely overran ws_size -> GPU fault).
  // region        floats    live (launch #)
  // [0,8)   xn      8M      1-10
  // [8,16)  q_sc    8M      3-9    then gate(lo) 10-11
  // [16,24) k_sc    8M      5-9    then gate(hi) 10-11
  // [24,40) v_sc   16M      7-9    then og       11-12
  // [40,48) pre     8M      2-5 (q_pre then k_pre)
  // [40,56) v_pre  16M      6-7    then o_scan   9-11
  // [56,..) g_arr/b_arr 64K+64K    8-9
  float* xn     = ws + 0;
  float* q_sc   = ws + 8 * M1;
  float* k_sc   = ws + 16 * M1;
  float* v_sc   = ws + 24 * M1;
  float* pre    = ws + 40 * M1;   // q_pre, then k_pre
  float* v_pre  = ws + 40 * M1;   // after k_pre is dead
  float* o_scan = ws + 40 * M1;   // after v_pre is dead
  float* gate   = ws + 8 * M1;    // after q_sc/k_sc are dead
  float* og     = ws + 24 * M1;   // after v_sc is dead
  float* g_arr  = ws + 56 * M1;
  float* b_arr  = ws + 56 * M1 + 65536;

  k_rms_row<<<TSEQ, 256, 0, stream>>>(x, norm_s, xn);                                   // 1

  k_gemm_tn<<<dim3(16, 32), 256, 0, stream>>>(xn, wq, pre, KEYDIM, DMODEL);             // 2
  k_conv_qk<<<dim3(TSEQ, NH), 128, 0, stream>>>(pre, qconv, q_sc, 0.08838834764831845f);// 3 (DK^-0.5)
  k_gemm_tn<<<dim3(16, 32), 256, 0, stream>>>(xn, wk, pre, KEYDIM, DMODEL);             // 4
  k_conv_qk<<<dim3(TSEQ, NH), 128, 0, stream>>>(pre, kconv, k_sc, 1.0f);                // 5
  k_gemm_tn<<<dim3(32, 32), 256, 0, stream>>>(xn, wv, v_pre, VALDIM, DMODEL);           // 6
  k_conv_v<<<dim3(TSEQ, NH), 256, 0, stream>>>(v_pre, vconv, v_sc);                     // 7
  k_ab<<<TSEQ, 256, 0, stream>>>(xn, a_proj, b_proj, A_log, dt_bias, g_arr, b_arr);     // 8

  k_scan<<<dim3(8, NH), 256, 0, stream>>>(q_sc, k_sc, v_sc, g_arr, b_arr, o_scan);      // 9

  k_gemm_tn<<<dim3(32, 32), 256, 0, stream>>>(xn, g_proj, gate, VALDIM, DMODEL);        // 10
  k_ognorm<<<dim3(TSEQ, NH), 256, 0, stream>>>(o_scan, gate, o_norm_s, og);             // 11

  k_gemm_tn<<<dim3(16, 32), 256, 0, stream>>>(og, wo, out, DMODEL, VALDIM);             // 12
  k_final_rms<<<TSEQ, 256, 0, stream>>>(x, final_s, out);                               // 13
}

// Round 5
// 2441.974 us; speedup vs baseline: 2.1679x; 2.1679x over previous
//
#include <hip/hip_runtime.h>
#include <cstdint>

#define TSEQ 4096
#define DMODEL 2048
#define NH 16
#define HDK 128
#define HDV 256
#define KEYDIM (NH * HDK)   // 2048
#define VALDIM (NH * HDV)   // 4096
#define SCHUNK 32

typedef __attribute__((ext_vector_type(8))) short short8v;
typedef __attribute__((ext_vector_type(4))) float f32x4;
#define MFMA_BF16 __builtin_amdgcn_mfma_f32_16x16x32_bf16

static __device__ __forceinline__ float sigmoidf_(float x) { return 1.f / (1.f + __expf(-x)); }
static __device__ __forceinline__ float siluf_(float x)    { return x / (1.f + __expf(-x)); }
static __device__ __forceinline__ float softplusf_(float x){ return (x > 20.f) ? x : log1pf(__expf(x)); }

static __device__ __forceinline__ ushort bf16r(float x) {   // RNE fp32->bf16
  unsigned u = __float_as_uint(x);
  return (ushort)((u + 0x7FFFu + ((u >> 16) & 1u)) >> 16);
}
static __device__ __forceinline__ float bf16tof(ushort h) {
  return __uint_as_float(((unsigned)h) << 16);
}

// DPP cross-lane add (VALU latency, no DS op). CTRL: 0xB1=xor1(quad), 0x4E=xor2(quad),
// 0x141=row_half_mirror (pairs the two quads within an 8-lane group), 0x140=row_mirror.
template <int CTRL>
static __device__ __forceinline__ float dpp_add(float v) {
  int m = __builtin_amdgcn_update_dpp(0, __float_as_int(v), CTRL, 0xF, 0xF, true);
  return v + __int_as_float(m);
}

// block-wide sum; NW = number of waves in block
template <int NW>
static __device__ __forceinline__ float block_sum(float v, float* red) {
  #pragma unroll
  for (int off = 1; off < 64; off <<= 1) v += __shfl_xor(v, off);
  if ((threadIdx.x & 63) == 0) red[threadIdx.x >> 6] = v;
  __syncthreads();
  float t = 0.f;
  #pragma unroll
  for (int i = 0; i < NW; ++i) t += red[i];
  return t;
}

// ---------------- rmsnorm of input rows ----------------
__global__ __launch_bounds__(256) void k_rms_row(const float* __restrict__ in,
                                                 const float* __restrict__ w,
                                                 float* __restrict__ out) {
  __shared__ float red[4];
  const int t = blockIdx.x;
  const float4* r4 = (const float4*)(in + (size_t)t * DMODEL);
  float4 v0 = r4[threadIdx.x];
  float4 v1 = r4[threadIdx.x + 256];
  float s = v0.x*v0.x + v0.y*v0.y + v0.z*v0.z + v0.w*v0.w
          + v1.x*v1.x + v1.y*v1.y + v1.z*v1.z + v1.w*v1.w;
  float tot = block_sum<4>(s, red);
  float inv = rsqrtf(tot * (1.f / DMODEL) + 1e-5f);
  const float4* w4 = (const float4*)w;
  float4 wa = w4[threadIdx.x], wb = w4[threadIdx.x + 256];
  float4 o0, o1;
  o0.x = v0.x * inv * wa.x; o0.y = v0.y * inv * wa.y; o0.z = v0.z * inv * wa.z; o0.w = v0.w * inv * wa.w;
  o1.x = v1.x * inv * wb.x; o1.y = v1.y * inv * wb.y; o1.z = v1.z * inv * wb.z; o1.w = v1.w * inv * wb.w;
  float4* dst = (float4*)(out + (size_t)t * DMODEL);
  dst[threadIdx.x] = o0;
  dst[threadIdx.x + 256] = o1;
}

// ---------------- final residual + rmsnorm (in-place on io) ----------------
__global__ __launch_bounds__(256) void k_final_rms(const float* __restrict__ x,
                                                   const float* __restrict__ w,
                                                   float* __restrict__ io) {
  __shared__ float red[4];
  const int t = blockIdx.x;
  const float4* x4 = (const float4*)(x + (size_t)t * DMODEL);
  float4* io4 = (float4*)(io + (size_t)t * DMODEL);
  float4 v0 = x4[threadIdx.x];
  float4 v1 = x4[threadIdx.x + 256];
  float4 u0 = io4[threadIdx.x];
  float4 u1 = io4[threadIdx.x + 256];
  v0.x += u0.x; v0.y += u0.y; v0.z += u0.z; v0.w += u0.w;
  v1.x += u1.x; v1.y += u1.y; v1.z += u1.z; v1.w += u1.w;
  float s = v0.x*v0.x + v0.y*v0.y + v0.z*v0.z + v0.w*v0.w
          + v1.x*v1.x + v1.y*v1.y + v1.z*v1.z + v1.w*v1.w;
  float tot = block_sum<4>(s, red);
  float inv = rsqrtf(tot * (1.f / DMODEL) + 1e-5f);
  const float4* w4 = (const float4*)w;
  float4 wa = w4[threadIdx.x], wb = w4[threadIdx.x + 256];
  float4 o0, o1;
  o0.x = v0.x * inv * wa.x; o0.y = v0.y * inv * wa.y; o0.z = v0.z * inv * wa.z; o0.w = v0.w * inv * wa.w;
  o1.x = v1.x * inv * wb.x; o1.y = v1.y * inv * wb.y; o1.z = v1.z * inv * wb.z; o1.w = v1.w * inv * wb.w;
  io4[threadIdx.x] = o0;
  io4[threadIdx.x + 256] = o1;
}

// ---------------- split-bf16 MFMA GEMM: C[m][n] = sum_k A[m][k]*B[n][k] ----------------
// fp32 inputs are split in-kernel into bf16 hi+lo planes; 3 MFMAs (hh, hl, lh)
// recover ~2^-17 relative accuracy. Tile 128x128xBK32, 4 waves (2x2 quadrants of 64x64),
// LDS rows padded to 40 bf16 so b128 fragment reads are ~conflict-free.
// Requires M%128==0, N%128==0, K%32==0 (true for all call sites).
__global__ __launch_bounds__(256, 2) void k_gemm_split(const float* __restrict__ A,
                                                       const float* __restrict__ B,
                                                       float* __restrict__ C,
                                                       int N, int K) {
  __shared__ __align__(16) ushort Ah[128 * 40];
  __shared__ __align__(16) ushort Al[128 * 40];
  __shared__ __align__(16) ushort Bh[128 * 40];
  __shared__ __align__(16) ushort Bl[128 * 40];
  const int tid = threadIdx.x;
  const int bm = blockIdx.y * 128, bn = blockIdx.x * 128;
  const int l = tid & 63, w = tid >> 6;
  const int wrow = (w >> 1) * 64, wcol = (w & 1) * 64;
  const int fr = l & 15, kg = l >> 4;
  const int r0 = tid >> 2, r1 = (tid + 256) >> 2;   // staging rows (0..63 / 64..127)
  const int q0 = tid & 3;                            // k-quarter (8 floats)

  f32x4 acc[4][4];
  #pragma unroll
  for (int i = 0; i < 4; ++i)
    #pragma unroll
    for (int j = 0; j < 4; ++j) {
      f32x4 z = {0.f, 0.f, 0.f, 0.f};
      acc[i][j] = z;
    }

  float4 rawA[2][2], rawB[2][2];     // raw fp32 staging regs
  short8v sAh[2], sAl[2], sBh[2], sBl[2];

#define G_LOAD(K0)                                                            \
  {                                                                           \
    const float* pa0 = A + (size_t)(bm + r0) * K + (K0) + q0 * 8;             \
    const float* pa1 = A + (size_t)(bm + r1) * K + (K0) + q0 * 8;             \
    const float* pb0 = B + (size_t)(bn + r0) * K + (K0) + q0 * 8;             \
    const float* pb1 = B + (size_t)(bn + r1) * K + (K0) + q0 * 8;             \
    rawA[0][0] = *(const float4*)pa0; rawA[0][1] = *(const float4*)(pa0 + 4); \
    rawA[1][0] = *(const float4*)pa1; rawA[1][1] = *(const float4*)(pa1 + 4); \
    rawB[0][0] = *(const float4*)pb0; rawB[0][1] = *(const float4*)(pb0 + 4); \
    rawB[1][0] = *(const float4*)pb1; rawB[1][1] = *(const float4*)(pb1 + 4); \
  }

#define G_CVT()                                                               \
  {                                                                           \
    _Pragma("unroll")                                                         \
    for (int jj = 0; jj < 2; ++jj) {                                          \
      float xa[8] = {rawA[jj][0].x, rawA[jj][0].y, rawA[jj][0].z, rawA[jj][0].w, \
                     rawA[jj][1].x, rawA[jj][1].y, rawA[jj][1].z, rawA[jj][1].w};\
      float xb[8] = {rawB[jj][0].x, rawB[jj][0].y, rawB[jj][0].z, rawB[jj][0].w, \
                     rawB[jj][1].x, rawB[jj][1].y, rawB[jj][1].z, rawB[jj][1].w};\
      _Pragma("unroll")                                                       \
      for (int e = 0; e < 8; ++e) {                                           \
        ushort ha = bf16r(xa[e]);                                             \
        sAh[jj][e] = (short)ha;                                               \
        sAl[jj][e] = (short)bf16r(xa[e] - bf16tof(ha));                       \
        ushort hb = bf16r(xb[e]);                                             \
        sBh[jj][e] = (short)hb;                                               \
        sBl[jj][e] = (short)bf16r(xb[e] - bf16tof(hb));                       \
      }                                                                       \
    }                                                                         \
  }

  G_LOAD(0);
  G_CVT();

  for (int k0 = 0; k0 < K; k0 += 32) {
    __syncthreads();
    *(short8v*)&Ah[r0 * 40 + q0 * 8] = sAh[0];
    *(short8v*)&Al[r0 * 40 + q0 * 8] = sAl[0];
    *(short8v*)&Ah[r1 * 40 + q0 * 8] = sAh[1];
    *(short8v*)&Al[r1 * 40 + q0 * 8] = sAl[1];
    *(short8v*)&Bh[r0 * 40 + q0 * 8] = sBh[0];
    *(short8v*)&Bl[r0 * 40 + q0 * 8] = sBl[0];
    *(short8v*)&Bh[r1 * 40 + q0 * 8] = sBh[1];
    *(short8v*)&Bl[r1 * 40 + q0 * 8] = sBl[1];
    __syncthreads();

    const bool more = (k0 + 32) < K;
    if (more) G_LOAD(k0 + 32);      // latency overlaps the MFMA block below

    short8v bh0 = *(const short8v*)&Bh[(wcol +  0 + fr) * 40 + kg * 8];
    short8v bh1 = *(const short8v*)&Bh[(wcol + 16 + fr) * 40 + kg * 8];
    short8v bh2 = *(const short8v*)&Bh[(wcol + 32 + fr) * 40 + kg * 8];
    short8v bh3 = *(const short8v*)&Bh[(wcol + 48 + fr) * 40 + kg * 8];
    short8v bl0 = *(const short8v*)&Bl[(wcol +  0 + fr) * 40 + kg * 8];
    short8v bl1 = *(const short8v*)&Bl[(wcol + 16 + fr) * 40 + kg * 8];
    short8v bl2 = *(const short8v*)&Bl[(wcol + 32 + fr) * 40 + kg * 8];
    short8v bl3 = *(const short8v*)&Bl[(wcol + 48 + fr) * 40 + kg * 8];
    #pragma unroll
    for (int fi = 0; fi < 4; ++fi) {
      const int ar = (wrow + fi * 16 + fr) * 40 + kg * 8;
      short8v ah = *(const short8v*)&Ah[ar];
      short8v al = *(const short8v*)&Al[ar];
      acc[fi][0] = MFMA_BF16(ah, bh0, acc[fi][0], 0, 0, 0);
      acc[fi][1] = MFMA_BF16(ah, bh1, acc[fi][1], 0, 0, 0);
      acc[fi][2] = MFMA_BF16(ah, bh2, acc[fi][2], 0, 0, 0);
      acc[fi][3] = MFMA_BF16(ah, bh3, acc[fi][3], 0, 0, 0);
      acc[fi][0] = MFMA_BF16(ah, bl0, acc[fi][0], 0, 0, 0);
      acc[fi][1] = MFMA_BF16(ah, bl1, acc[fi][1], 0, 0, 0);
      acc[fi][2] = MFMA_BF16(ah, bl2, acc[fi][2], 0, 0, 0);
      acc[fi][3] = MFMA_BF16(ah, bl3, acc[fi][3], 0, 0, 0);
      acc[fi][0] = MFMA_BF16(al, bh0, acc[fi][0], 0, 0, 0);
      acc[fi][1] = MFMA_BF16(al, bh1, acc[fi][1], 0, 0, 0);
      acc[fi][2] = MFMA_BF16(al, bh2, acc[fi][2], 0, 0, 0);
      acc[fi][3] = MFMA_BF16(al, bh3, acc[fi][3], 0, 0, 0);
    }
    if (more) G_CVT();
  }
#undef G_LOAD
#undef G_CVT

  // epilogue: C/D layout col=lane&15, row=(lane>>4)*4+reg  [m89-verified]
  #pragma unroll
  for (int fi = 0; fi < 4; ++fi)
    #pragma unroll
    for (int fj = 0; fj < 4; ++fj) {
      #pragma unroll
      for (int r = 0; r < 4; ++r) {
        C[(size_t)(bm + wrow + fi * 16 + kg * 4 + r) * N + (bn + wcol + fj * 16 + fr)] =
            acc[fi][fj][r];
      }
    }
}

// ---------------- a/b projections (N=16 each) + activations ----------------
__global__ __launch_bounds__(256) void k_ab(const float* __restrict__ xn,
                                            const float* __restrict__ a_proj,
                                            const float* __restrict__ b_proj,
                                            const float* __restrict__ A_log,
                                            const float* __restrict__ dt_bias,
                                            float* __restrict__ g_arr,
                                            float* __restrict__ b_arr) {
  __shared__ __align__(16) float xrow[DMODEL];
  const int t = blockIdx.x;
  const float4* src = (const float4*)(xn + (size_t)t * DMODEL);
  ((float4*)xrow)[threadIdx.x] = src[threadIdx.x];
  ((float4*)xrow)[threadIdx.x + 256] = src[threadIdx.x + 256];
  __syncthreads();
  const int d = threadIdx.x >> 3, p = threadIdx.x & 7;   // 32 dots x 8 lanes
  const float* wrow = (d < NH) ? (a_proj + (size_t)d * DMODEL)
                               : (b_proj + (size_t)(d - NH) * DMODEL);
  const float4* w4 = (const float4*)wrow;
  const float4* x4 = (const float4*)xrow;
  float s = 0.f;
  #pragma unroll 4
  for (int j = p; j < DMODEL / 4; j += 8) {
    float4 xv = x4[j], wv = w4[j];
    s += xv.x * wv.x + xv.y * wv.y + xv.z * wv.z + xv.w * wv.w;
  }
  s += __shfl_xor(s, 1);
  s += __shfl_xor(s, 2);
  s += __shfl_xor(s, 4);
  if (p == 0) {
    if (d < NH) {
      float dt = softplusf_(s + dt_bias[d]);
      g_arr[t * NH + d] = -__expf(A_log[d]) * dt;
    } else {
      b_arr[t * NH + (d - NH)] = sigmoidf_(s);
    }
  }
}

// ---------------- conv(K=4) + silu + l2norm for q/k; writes [H][T][128] ----------------
__global__ __launch_bounds__(128) void k_conv_qk(const float* __restrict__ pre,
                                                 const float* __restrict__ w,
                                                 float* __restrict__ out,
                                                 float scale) {
  __shared__ float red[2];
  const int t = blockIdx.x, hh = blockIdx.y, c = threadIdx.x;
  const int ch = hh * HDK + c;
  float acc = 0.f;
  #pragma unroll
  for (int i = 0; i < 4; ++i) {
    int tt = t - 3 + i;
    float xv = (tt >= 0) ? pre[(size_t)tt * KEYDIM + ch] : 0.f;
    acc = fmaf(w[ch * 4 + i], xv, acc);
  }
  float y = siluf_(acc);
  float tot = block_sum<2>(y * y, red);
  float inv = scale / fmaxf(sqrtf(tot), 1e-12f);
  out[((size_t)hh * TSEQ + t) * HDK + c] = y * inv;
}

// ---------------- conv(K=4) + silu for v; writes [H][T][256] ----------------
__global__ __launch_bounds__(256) void k_conv_v(const float* __restrict__ pre,
                                                const float* __restrict__ w,
                                                float* __restrict__ out) {
  const int t = blockIdx.x, hh = blockIdx.y, c = threadIdx.x;
  const int ch = hh * HDV + c;
  float acc = 0.f;
  #pragma unroll
  for (int i = 0; i < 4; ++i) {
    int tt = t - 3 + i;
    float xv = (tt >= 0) ? pre[(size_t)tt * VALDIM + ch] : 0.f;
    acc = fmaf(w[ch * 4 + i], xv, acc);
  }
  out[((size_t)hh * TSEQ + t) * HDV + c] = siluf_(acc);
}

// ---------------- qk[t][h] = q[t,h,:].k[t,h,:] (hoisted off the scan's serial path) ----
__global__ __launch_bounds__(256) void k_qk(const float* __restrict__ q,
                                            const float* __restrict__ k,
                                            float* __restrict__ qk) {
  const int t = blockIdx.x, h = threadIdx.x >> 4, ln = threadIdx.x & 15;
  const float4* qp = (const float4*)(q + ((size_t)h * TSEQ + t) * HDK + ln * 8);
  const float4* kp = (const float4*)(k + ((size_t)h * TSEQ + t) * HDK + ln * 8);
  float4 a0 = qp[0], a1 = qp[1], b0 = kp[0], b1 = kp[1];
  float s = a0.x*b0.x + a0.y*b0.y + a0.z*b0.z + a0.w*b0.w
          + a1.x*b1.x + a1.y*b1.y + a1.z*b1.z + a1.w*b1.w;
  s = dpp_add<0xB1>(s);   // xor1
  s = dpp_add<0x4E>(s);   // xor2
  s = dpp_add<0x141>(s);  // row_half_mirror: quads 0<->1 within 8
  s = dpp_add<0x140>(s);  // row_mirror: halves of the 16-row
  if (ln == 0) qk[t * NH + h] = s;
}

// ---------------- gated delta scan ----------------
// grid (8 dv-slices, 16 heads), 256 threads. Thread (dv=tid>>3, dkg=tid&7) owns
// h[dkg*16..+15][dv]. Per-step: DPP-only 8-lane reduce, register ping-pong prefetch
// of next step's k/q/v/scalars, double-buffered chunk staging via registers.
static __device__ __forceinline__ int sslot(int m) { return 4 * (m & 7) + (m >> 3); }

__global__ __launch_bounds__(256) void k_scan(const float* __restrict__ qs,
                                              const float* __restrict__ ks,
                                              const float* __restrict__ vs,
                                              const float* __restrict__ g_arr,
                                              const float* __restrict__ b_arr,
                                              const float* __restrict__ qk_arr,
                                              float* __restrict__ o) {
  __shared__ __align__(16) float kt[(SCHUNK + 1) * HDK];   // +1 row: tail-prefetch pad
  __shared__ __align__(16) float qt[(SCHUNK + 1) * HDK];
  __shared__ __align__(16) float vt[(SCHUNK + 1) * 32];
  __shared__ float gt[SCHUNK + 1], bt[SCHUNK + 1], qkt[SCHUNK + 1];
  const int hh = blockIdx.y, dvb = blockIdx.x;
  const int tid = threadIdx.x;
  const int dv = tid >> 3, dkg = tid & 7;
  const int s0 = 16 * (dkg & 1) + (dkg >> 1);  // slot of chunk 4*dkg+r is s0+4r
  float hreg[16];
  #pragma unroll
  for (int i = 0; i < 16; ++i) hreg[i] = 0.f;
  const float* kb = ks + (size_t)hh * TSEQ * HDK;
  const float* qb = qs + (size_t)hh * TSEQ * HDK;
  const float* vb = vs + (size_t)hh * TSEQ * HDV + dvb * 32;

  float4 ksr[4], qsr[4], vsr;
  float gsr = 0.f, bsr = 0.f, qksr = 0.f;

#define LOADG(T0)                                                              \
  {                                                                            \
    _Pragma("unroll")                                                          \
    for (int i = 0; i < 4; ++i) {                                              \
      int f4 = tid + i * 256, tt_ = f4 >> 5, m_ = f4 & 31;                     \
      ksr[i] = *(const float4*)(kb + (size_t)((T0) + tt_) * HDK + m_ * 4);     \
      qsr[i] = *(const float4*)(qb + (size_t)((T0) + tt_) * HDK + m_ * 4);     \
    }                                                                          \
    vsr = *(const float4*)(vb + (size_t)((T0) + (tid >> 3)) * HDV + (tid & 7) * 4); \
    if (tid < SCHUNK) {                                                        \
      gsr = g_arr[((T0) + tid) * NH + hh];                                     \
      bsr = b_arr[((T0) + tid) * NH + hh];                                     \
      qksr = qk_arr[((T0) + tid) * NH + hh];                                   \
    }                                                                          \
  }

#define WRITES()                                                               \
  {                                                                            \
    _Pragma("unroll")                                                          \
    for (int i = 0; i < 4; ++i) {                                              \
      int f4 = tid + i * 256, tt_ = f4 >> 5, m_ = f4 & 31;                     \
      int off = tt_ * HDK + sslot(m_) * 4;                                     \
      *(float4*)(kt + off) = ksr[i];                                           \
      *(float4*)(qt + off) = qsr[i];                                           \
    }                                                                          \
    *(float4*)(vt + (tid >> 3) * 32 + (tid & 7) * 4) = vsr;                    \
    if (tid < SCHUNK) { gt[tid] = gsr; bt[tid] = bsr; qkt[tid] = qksr; }       \
  }

#define SCAN_LOAD(S, KA, QA, EG, VV, BB, QQ)                                   \
  {                                                                            \
    const float4* kr_ = (const float4*)(kt + (S) * HDK);                       \
    const float4* qr_ = (const float4*)(qt + (S) * HDK);                       \
    *(float4*)(KA + 0)  = kr_[s0];      *(float4*)(KA + 4)  = kr_[s0 + 4];     \
    *(float4*)(KA + 8)  = kr_[s0 + 8];  *(float4*)(KA + 12) = kr_[s0 + 12];    \
    *(float4*)(QA + 0)  = qr_[s0];      *(float4*)(QA + 4)  = qr_[s0 + 4];     \
    *(float4*)(QA + 8)  = qr_[s0 + 8];  *(float4*)(QA + 12) = qr_[s0 + 12];    \
    EG = __expf(gt[(S)]); VV = vt[(S) * 32 + dv]; BB = bt[(S)]; QQ = qkt[(S)]; \
  }

#define SCAN_STEP(KA, QA, EG, VV, BB, QQ, T)                                   \
  {                                                                            \
    float p0 = 0.f, p1 = 0.f, p2 = 0.f, p3 = 0.f;                              \
    float u0 = 0.f, u1 = 0.f, u2 = 0.f, u3 = 0.f;                              \
    _Pragma("unroll")                                                          \
    for (int i = 0; i < 4; ++i) {                                              \
      p0 = fmaf(KA[i],      hreg[i],      p0);                                 \
      p1 = fmaf(KA[4 + i],  hreg[4 + i],  p1);                                 \
      p2 = fmaf(KA[8 + i],  hreg[8 + i],  p2);                                 \
      p3 = fmaf(KA[12 + i], hreg[12 + i], p3);                                 \
      u0 = fmaf(QA[i],      hreg[i],      u0);                                 \
      u1 = fmaf(QA[4 + i],  hreg[4 + i],  u1);                                 \
      u2 = fmaf(QA[8 + i],  hreg[8 + i],  u2);                                 \
      u3 = fmaf(QA[12 + i], hreg[12 + i], u3);                                 \
    }                                                                          \
    float skh = (p0 + p1) + (p2 + p3);                                         \
    float sqh = (u0 + u1) + (u2 + u3);                                         \
    skh = dpp_add<0xB1>(skh); skh = dpp_add<0x4E>(skh); skh = dpp_add<0x141>(skh); \
    sqh = dpp_add<0xB1>(sqh); sqh = dpp_add<0x4E>(sqh); sqh = dpp_add<0x141>(sqh); \
    float vadj = (VV - EG * skh) * BB;                                         \
    if (dkg == 0)                                                              \
      o[(size_t)(t0 + (T)) * VALDIM + hh * HDV + dvb * 32 + dv] =              \
          fmaf(EG, sqh, QQ * vadj);                                            \
    _Pragma("unroll")                                                          \
    for (int i = 0; i < 16; ++i) hreg[i] = fmaf(hreg[i], EG, KA[i] * vadj);    \
  }

  LOADG(0);
  WRITES();
  __syncthreads();

  for (int t0 = 0; t0 < TSEQ; t0 += SCHUNK) {
    const bool more = (t0 + SCHUNK) < TSEQ;
    if (more) LOADG(t0 + SCHUNK);    // global prefetch overlaps the 32 steps below

    float kaA[16], qaA[16], kaB[16], qaB[16];
    float egA, vvA, bbA, qqA, egB, vvB, bbB, qqB;
    SCAN_LOAD(0, kaA, qaA, egA, vvA, bbA, qqA);
    #pragma unroll 1
    for (int tt = 0; tt < SCHUNK; tt += 2) {
      SCAN_LOAD(tt + 1, kaB, qaB, egB, vvB, bbB, qqB);
      SCAN_STEP(kaA, qaA, egA, vvA, bbA, qqA, tt);
      SCAN_LOAD(tt + 2, kaA, qaA, egA, vvA, bbA, qqA);   // tt=30 -> pad row 32 (unused)
      SCAN_STEP(kaB, qaB, egB, vvB, bbB, qqB, tt + 1);
    }
    __syncthreads();
    if (more) WRITES();
    __syncthreads();
  }
#undef LOADG
#undef WRITES
#undef SCAN_LOAD
#undef SCAN_STEP
}

// ---------------- per-(t,h) rmsnorm of o * silu(gate) ----------------
__global__ __launch_bounds__(256) void k_ognorm(const float* __restrict__ o,
                                                const float* __restrict__ gate,
                                                const float* __restrict__ w,
                                                float* __restrict__ og) {
  __shared__ float red[4];
  const int t = blockIdx.x, hh = blockIdx.y, c = threadIdx.x;
  size_t idx = (size_t)t * VALDIM + hh * HDV + c;
  float v = o[idx];
  float tot = block_sum<4>(v * v, red);
  float inv = rsqrtf(tot * (1.f / HDV) + 1e-5f);
  float gv = gate[idx];
  og[idx] = v * inv * w[c] * siluf_(gv);
}

extern "C" void kernel_launch(void* const* d_in, const int* in_sizes, int n_in,
                              void* d_out, int out_size, void* d_ws, size_t ws_size,
                              hipStream_t stream) {
  const float* x        = (const float*)d_in[0];
  const float* norm_s   = (const float*)d_in[1];
  const float* final_s  = (const float*)d_in[2];
  const float* wq       = (const float*)d_in[3];
  const float* wk       = (const float*)d_in[4];
  const float* wv       = (const float*)d_in[5];
  const float* qconv    = (const float*)d_in[6];
  const float* kconv    = (const float*)d_in[7];
  const float* vconv    = (const float*)d_in[8];
  const float* a_proj   = (const float*)d_in[9];
  const float* A_log    = (const float*)d_in[10];
  const float* dt_bias  = (const float*)d_in[11];
  const float* b_proj   = (const float*)d_in[12];
  const float* g_proj   = (const float*)d_in[13];
  const float* o_norm_s = (const float*)d_in[14];
  const float* wo       = (const float*)d_in[15];
  float* out = (float*)d_out;
  float* ws  = (float*)d_ws;

  const size_t M1 = 1u << 20;
  // Compact live-range-overlapped workspace: peak = 56*M1 + 192K floats (~224.8 MB)
  float* xn     = ws + 0;
  float* q_sc   = ws + 8 * M1;
  float* k_sc   = ws + 16 * M1;
  float* v_sc   = ws + 24 * M1;
  float* pre    = ws + 40 * M1;   // q_pre, then k_pre
  float* v_pre  = ws + 40 * M1;   // after k_pre is dead
  float* o_scan = ws + 40 * M1;   // after v_pre is dead
  float* gate   = ws + 8 * M1;    // after q_sc/k_sc are dead
  float* og     = ws + 24 * M1;   // after v_sc is dead
  float* g_arr  = ws + 56 * M1;
  float* b_arr  = ws + 56 * M1 + 65536;
  float* qk_arr = ws + 56 * M1 + 131072;

  k_rms_row<<<TSEQ, 256, 0, stream>>>(x, norm_s, xn);                                    // 1

  k_gemm_split<<<dim3(16, 32), 256, 0, stream>>>(xn, wq, pre, KEYDIM, DMODEL);           // 2
  k_conv_qk<<<dim3(TSEQ, NH), 128, 0, stream>>>(pre, qconv, q_sc, 0.08838834764831845f); // 3 (DK^-0.5)
  k_gemm_split<<<dim3(16, 32), 256, 0, stream>>>(xn, wk, pre, KEYDIM, DMODEL);           // 4
  k_conv_qk<<<dim3(TSEQ, NH), 128, 0, stream>>>(pre, kconv, k_sc, 1.0f);                 // 5
  k_qk<<<TSEQ, 256, 0, stream>>>(q_sc, k_sc, qk_arr);                                    // 6
  k_gemm_split<<<dim3(32, 32), 256, 0, stream>>>(xn, wv, v_pre, VALDIM, DMODEL);         // 7
  k_conv_v<<<dim3(TSEQ, NH), 256, 0, stream>>>(v_pre, vconv, v_sc);                      // 8
  k_ab<<<TSEQ, 256, 0, stream>>>(xn, a_proj, b_proj, A_log, dt_bias, g_arr, b_arr);      // 9

  k_scan<<<dim3(8, NH), 256, 0, stream>>>(q_sc, k_sc, v_sc, g_arr, b_arr, qk_arr, o_scan);// 10

  k_gemm_split<<<dim3(32, 32), 256, 0, stream>>>(xn, g_proj, gate, VALDIM, DMODEL);      // 11
  k_ognorm<<<dim3(TSEQ, NH), 256, 0, stream>>>(o_scan, gate, o_norm_s, og);              // 12

  k_gemm_split<<<dim3(16, 32), 256, 0, stream>>>(og, wo, out, DMODEL, VALDIM);           // 13
  k_final_rms<<<TSEQ, 256, 0, stream>>>(x, final_s, out);                                // 14
}